// Round 1
// 1230.910 us; speedup vs baseline: 1.4125x; 1.4125x over previous
//
#include <hip/hip_runtime.h>
#include <hip/hip_bf16.h>
#include <cstdint>

#define NBATCH   16
#define NPIX     49152
#define NBUCKETS 8
#define C_IN     16
#define GRIDSZ   (NBATCH * NPIX * NBUCKETS)   // 6,291,456 cells
#define ROWS     (NBATCH * NPIX)              // 786,432 output rows
#define PROJ_IN  136
#define PROJ_MID 128
#define OUT_DIM  64
#define LN_EPS   1e-5f

// binning parameters: one bin == one 64-row fused-kernel group == 512 cells
#define NBINS    (GRIDSZ / 512)               // 12,288
#define CAP      768                          // slots per bin (lambda~326, >20 sigma)

typedef __attribute__((ext_vector_type(8))) short bf16x8;
typedef __attribute__((ext_vector_type(4))) float f32x4;
typedef __attribute__((ext_vector_type(4))) int   i32x4;

union FragU { i32x4 i; bf16x8 b; };

__device__ __forceinline__ uint32_t bf16_rn(float f) {
    uint32_t u = __float_as_uint(f);
    return (u + 0x7fffu + ((u >> 16) & 1u)) >> 16;
}
__device__ __forceinline__ uint32_t pack_bf16x2(float lo, float hi) {
    return bf16_rn(lo) | (bf16_rn(hi) << 16);
}

// ---------- kernel 1: bin points (bump-allocate packed pairs per bin) ----------
__global__ void bin_kernel(const int* __restrict__ bidx,
                           const int* __restrict__ pix,
                           const int* __restrict__ bkt,
                           uint32_t* __restrict__ cnt,
                           uint32_t* __restrict__ pairs,
                           int npoints) {
    int i = blockIdx.x * blockDim.x + threadIdx.x;
    if (i >= npoints) return;
    int flat = (bidx[i] * NPIX + pix[i]) * NBUCKETS + bkt[i];
    int b = flat >> 9;
    uint32_t slot = atomicAdd(&cnt[b], 1u);
    if (slot < CAP)
        pairs[(size_t)b * CAP + slot] = ((uint32_t)i << 9) | (uint32_t)(flat & 511);
}

// ---------- kernel 2: per-bin LDS aggregation -> bf16 means + presence bytes ----------
__global__ __launch_bounds__(256) void agg_kernel(const float* __restrict__ x,
                                                  const uint32_t* __restrict__ cnt,
                                                  const uint32_t* __restrict__ pairs,
                                                  uint16_t* __restrict__ means,
                                                  uint8_t* __restrict__ pres_out) {
    // 512 cells x (16 sums + 1 count), stride 17 floats breaks bank alignment
    __shared__ float lsum[512 * 17];           // 34,816 B
    const int tid = threadIdx.x;
    const int b = blockIdx.x;

    for (int k = tid; k < 512 * 17; k += 256) lsum[k] = 0.f;
    __syncthreads();

    int n = (int)cnt[b];
    if (n > CAP) n = CAP;
    const uint32_t* pb = pairs + (size_t)b * CAP;
    const int sub = tid & 3;

    // 4 lanes per pair: coalesced 64B x-row reads, ds_add_f32 accumulation
    for (int g = tid >> 2; g < n; g += 64) {
        uint32_t val = pb[g];
        int i = (int)(val >> 9);
        int cell = (int)(val & 511u);
        const float4 v = *(const float4*)(x + (size_t)i * C_IN + sub * 4);
        float* dst = lsum + cell * 17 + sub * 4;
        unsafeAtomicAdd(dst + 0, v.x);
        unsafeAtomicAdd(dst + 1, v.y);
        unsafeAtomicAdd(dst + 2, v.z);
        unsafeAtomicAdd(dst + 3, v.w);
        if (sub == 0) unsafeAtomicAdd(lsum + cell * 17 + 16, 1.0f);
    }
    __syncthreads();

    // presence byte per row (64 rows per bin)
    if (tid < 64) {
        uint32_t byte = 0;
        #pragma unroll
        for (int j = 0; j < 8; ++j)
            if (lsum[(tid * 8 + j) * 17 + 16] > 0.f) byte |= (1u << j);
        pres_out[(size_t)b * 64 + tid] = (uint8_t)byte;
    }

    // bf16 means, coalesced 32B per cell (every cell written -> no global memset)
    for (int cell = tid; cell < 512; cell += 256) {
        float c = lsum[cell * 17 + 16];
        float rcpv = (c > 0.f) ? (1.0f / c) : 0.f;
        uint32_t w[8];
        #pragma unroll
        for (int e = 0; e < 8; ++e)
            w[e] = pack_bf16x2(lsum[cell * 17 + 2 * e] * rcpv,
                               lsum[cell * 17 + 2 * e + 1] * rcpv);
        uint32_t* dst = (uint32_t*)(means + ((size_t)b * 64 + (cell >> 3)) * 128 + (cell & 7) * 16);
        i32x4 v0 = { (int)w[0], (int)w[1], (int)w[2], (int)w[3] };
        i32x4 v1 = { (int)w[4], (int)w[5], (int)w[6], (int)w[7] };
        *(i32x4*)dst = v0;
        *(i32x4*)(dst + 4) = v1;
    }
}

// ---------- kernel 3: MFMA fused proj1 -> LN -> SiLU -> proj2 ----------
// One wave per 16-row tile; block = 4 waves = 64 rows per iteration.
// mfma_f32_16x16x32_bf16:  A[m=lane&15][k=(lane>>4)*8+i]
//                          B[k=(lane>>4)*8+i][n=lane&15]
//                          D[row=(lane>>4)*4+reg][col=lane&15]
__global__ __launch_bounds__(256, 2) void fused_proj_kernel(
    const uint16_t* __restrict__ means, const uint8_t* __restrict__ presence,
    const float* __restrict__ W1, const float* __restrict__ b1,
    const float* __restrict__ gamma, const float* __restrict__ beta,
    const float* __restrict__ W2, const float* __restrict__ b2,
    float* __restrict__ out) {

    // W1 B-frags: ntile j in [0,8), kstep t in [0,5) (K padded 136->160), lane l.
    __shared__ uint32_t sW1[8 * 5 * 64 * 4];   // 40960 B
    // W2 B-frags: ntile j2 in [0,4), kstep t2 in [0,4).
    __shared__ uint32_t sW2[4 * 4 * 64 * 4];   // 16384 B
    // per-wave h roundtrip buffer: 16 rows x 136 bf16
    __shared__ uint16_t hbuf[4][16 * 136];     // 17408 B

    const int tid = threadIdx.x;

    // ---- stage W1 fragments ----
    for (int idx = tid; idx < 8 * 5 * 64; idx += 256) {
        int j = idx / 320, rem = idx % 320;
        int t = rem / 64, l = rem % 64;
        int qq = l >> 4, cc = l & 15;
        int n = j * 16 + cc;
        i32x4 w;
        #pragma unroll
        for (int p = 0; p < 4; ++p) {
            int k0 = t * 32 + qq * 8 + 2 * p;
            float f0 = (k0 < PROJ_IN) ? W1[k0 * PROJ_MID + n] : 0.f;
            float f1 = (k0 + 1 < PROJ_IN) ? W1[(k0 + 1) * PROJ_MID + n] : 0.f;
            w[p] = (int)pack_bf16x2(f0, f1);
        }
        *(i32x4*)&sW1[idx * 4] = w;
    }
    // ---- stage W2 fragments ----
    for (int idx = tid; idx < 4 * 4 * 64; idx += 256) {
        int j2 = idx / 256, rem = idx % 256;
        int t2 = rem / 64, l = rem % 64;
        int qq = l >> 4, cc = l & 15;
        int n = j2 * 16 + cc;
        i32x4 w;
        #pragma unroll
        for (int p = 0; p < 4; ++p) {
            int k0 = t2 * 32 + qq * 8 + 2 * p;
            w[p] = (int)pack_bf16x2(W2[k0 * OUT_DIM + n], W2[(k0 + 1) * OUT_DIM + n]);
        }
        *(i32x4*)&sW2[idx * 4] = w;
    }

    const int lane = tid & 63;
    const int wv   = tid >> 6;
    const int q    = lane >> 4;
    const int c    = lane & 15;

    // per-lane epilogue constants (col = 16j + c)
    float b1v[8], gav[8], bev[8], b2v[4];
    #pragma unroll
    for (int j = 0; j < 8; ++j) {
        b1v[j] = b1[16 * j + c];
        gav[j] = gamma[16 * j + c];
        bev[j] = beta[16 * j + c];
    }
    #pragma unroll
    for (int j2 = 0; j2 < 4; ++j2) b2v[j2] = b2[16 * j2 + c];

    __syncthreads();

    uint16_t* hb = hbuf[wv];

    for (int grp = blockIdx.x; grp < ROWS / 64; grp += gridDim.x) {
        const int rowbase = grp * 64 + wv * 16;
        const int myrow   = rowbase + c;          // row for A-frag loads (m = lane&15)

        // ---- A fragments: direct 16B loads of bf16 means ----
        const uint16_t* mrow = means + (size_t)myrow * 128;
        FragU afrag[5];
        #pragma unroll
        for (int t = 0; t < 4; ++t)
            afrag[t].i = *(const i32x4*)(mrow + t * 32 + q * 8);

        // t=4: presence (k=128..135) only valid in q==0 lanes, zero elsewhere
        const uint32_t pres = presence[myrow];
        #pragma unroll
        for (int p = 0; p < 4; ++p) {
            uint32_t lo = (q == 0 && (pres & (1u << (2 * p))))     ? 0x3F80u : 0u;
            uint32_t hi = (q == 0 && (pres & (1u << (2 * p + 1)))) ? 0x3F80u : 0u;
            afrag[4].i[p] = (int)(lo | (hi << 16));
        }

        // ---- GEMM1: h = A @ W1 ----
        f32x4 acc[8];
        #pragma unroll
        for (int j = 0; j < 8; ++j) acc[j] = (f32x4){0.f, 0.f, 0.f, 0.f};
        #pragma unroll
        for (int j = 0; j < 8; ++j) {
            #pragma unroll
            for (int t = 0; t < 5; ++t) {
                FragU w;
                w.i = *(const i32x4*)&sW1[((j * 5 + t) * 64 + lane) * 4];
                acc[j] = __builtin_amdgcn_mfma_f32_16x16x32_bf16(afrag[t].b, w.b, acc[j], 0, 0, 0);
            }
        }

        // ---- bias + LayerNorm + SiLU, write normalized h (bf16) to LDS ----
        #pragma unroll
        for (int r = 0; r < 4; ++r) {
            float h[8];
            float s1 = 0.f, s2 = 0.f;
            #pragma unroll
            for (int j = 0; j < 8; ++j) {
                h[j] = acc[j][r] + b1v[j];
                s1 += h[j];
                s2 += h[j] * h[j];
            }
            #pragma unroll
            for (int m = 1; m < 16; m <<= 1) {
                s1 += __shfl_xor(s1, m, 64);
                s2 += __shfl_xor(s2, m, 64);
            }
            float mu  = s1 * (1.0f / 128.0f);
            float var = s2 * (1.0f / 128.0f) - mu * mu;
            float rs  = rsqrtf(var + LN_EPS);
            int   row = q * 4 + r;
            #pragma unroll
            for (int j = 0; j < 8; ++j) {
                float z  = (h[j] - mu) * rs * gav[j] + bev[j];
                float sl = z / (1.0f + __expf(-z));
                hb[row * 136 + 16 * j + c] = (uint16_t)bf16_rn(sl);
            }
        }

        // ---- GEMM2: out = hn @ W2 (A2 from LDS roundtrip) ----
        FragU a2[4];
        #pragma unroll
        for (int t2 = 0; t2 < 4; ++t2) {
            a2[t2].i = *(const i32x4*)&((const uint32_t*)hb)[(c * 136 + t2 * 32 + q * 8) / 2];
        }
        f32x4 acc2[4];
        #pragma unroll
        for (int j2 = 0; j2 < 4; ++j2) acc2[j2] = (f32x4){0.f, 0.f, 0.f, 0.f};
        #pragma unroll
        for (int j2 = 0; j2 < 4; ++j2) {
            #pragma unroll
            for (int t2 = 0; t2 < 4; ++t2) {
                FragU w;
                w.i = *(const i32x4*)&sW2[((j2 * 4 + t2) * 64 + lane) * 4];
                acc2[j2] = __builtin_amdgcn_mfma_f32_16x16x32_bf16(a2[t2].b, w.b, acc2[j2], 0, 0, 0);
            }
        }

        // ---- epilogue: bias + store ----
        #pragma unroll
        for (int j2 = 0; j2 < 4; ++j2) {
            #pragma unroll
            for (int r = 0; r < 4; ++r) {
                out[(size_t)(rowbase + q * 4 + r) * OUT_DIM + 16 * j2 + c] = acc2[j2][r] + b2v[j2];
            }
        }
    }
}

// ---------- launcher ----------
extern "C" void kernel_launch(void* const* d_in, const int* in_sizes, int n_in,
                              void* d_out, int out_size, void* d_ws, size_t ws_size,
                              hipStream_t stream) {
    const float* x    = (const float*)d_in[0];
    const int*   bidx = (const int*)d_in[1];
    const int*   pix  = (const int*)d_in[2];
    const int*   bkt  = (const int*)d_in[3];
    const float* W1   = (const float*)d_in[6];
    const float* b1   = (const float*)d_in[7];
    const float* gmm  = (const float*)d_in[8];
    const float* bet  = (const float*)d_in[9];
    const float* W2   = (const float*)d_in[10];
    const float* b2   = (const float*)d_in[11];
    float* out = (float*)d_out;

    const int npoints = in_sizes[0] / C_IN;   // 4,000,000

    // workspace layout (all offsets multiple of 256B):
    //   means    : ROWS*128 bf16      = 201,326,592 B
    //   presence : ROWS bytes         =     786,432 B
    //   cnt      : NBINS u32          =      49,152 B
    //   pairs    : NBINS*CAP u32      =  37,748,736 B
    uint8_t* wsb = (uint8_t*)d_ws;
    uint16_t* means    = (uint16_t*)wsb;
    uint8_t*  presence = wsb + 201326592;
    uint32_t* cnt      = (uint32_t*)(wsb + 201326592 + 786432);
    uint32_t* pairs    = (uint32_t*)(wsb + 202162176);

    hipMemsetAsync(cnt, 0, (size_t)NBINS * 4, stream);

    {
        int grid = (npoints + 255) / 256;
        bin_kernel<<<grid, 256, 0, stream>>>(bidx, pix, bkt, cnt, pairs, npoints);
    }
    {
        agg_kernel<<<NBINS, 256, 0, stream>>>(x, cnt, pairs, means, presence);
    }
    {
        fused_proj_kernel<<<512, 256, 0, stream>>>(means, presence, W1, b1, gmm, bet, W2, b2, out);
    }
}